// Round 12
// baseline (110.467 us; speedup 1.0000x reference)
//
#include <hip/hip_runtime.h>

// Problem: B=2048, D=512, all fp32.
// q = query@Wq.T+bq ; k,v likewise. attn[b,i,j]=q_i*k_j (rank-1!),
// softmax over j, out[b,i] = sum_j softmax_j(q_i*k_j)*v_j.
//
// Round 16 (single-variable: gemm occupancy 3 -> 6 blocks/CU; attn
// byte-identical to r15):
//  - Every LDS-gemm variant so far ran 3 blocks/CU (12 waves/CU, 37% occ);
//    direct counters (r8/r10) showed all pipes <20% busy -> stall-bound.
//    Intra-wave scheduling variants were all neutral; the untried lever is
//    TLP. New geometry: 32x64 tile, LDS [2][96][32] f32 = 24 KiB ->
//    6 blocks/CU, grid (64,8,3)=1536 = exactly 6/CU = 6 waves/SIMD.
//  - Staging: 3x gload16/thread/step (row = h*32 + wv*8 + lane/8; the XOR
//    granule swizzle reduces to the same (lane&7)^(lane>>3) since
//    wv*8 = 0 mod 8). Wave tile 16x32 -> 1xA + 2xB frags, 6 MFMA/step.
//    Per-fragment arithmetic and K-order bit-identical -> absmax 0.0078125.
//  - Cost: B-tile DMA doubles (294 MB total, L2/L3-served) -- acceptable.
//
// Ledger: ~43.5us poison fill (77% HBM peak) + ~30us harness resets/gaps
// fixed; controllable = gemm (~21 -> target 12-15) + attn (~11, trans-bound
// at NGRID=64) + 2 launch gaps.

#define B_SZ 2048
#define D_SZ 512
#define LOG2E 1.44269504088896340736f
#define NGRID 64
#define SEG 136   // 128 floats payload + 8 pad: segment s starts at bank 8s

typedef __attribute__((ext_vector_type(2))) float  f32x2;
typedef __attribute__((ext_vector_type(4))) float  f32x4;
typedef __attribute__((ext_vector_type(8))) short  bf16x8;   // MFMA A/B carrier

__device__ __forceinline__ float exp2_raw(float x) {
#if defined(__has_builtin) && __has_builtin(__builtin_amdgcn_exp2f)
    return __builtin_amdgcn_exp2f(x);
#else
    return exp2f(x);
#endif
}

// Forced packed fp32 math (compiler emits scalar for f32x2 exprs otherwise).
__device__ __forceinline__ f32x2 pk_fma(f32x2 a, f32x2 b, f32x2 c) {
    f32x2 d;
    asm("v_pk_fma_f32 %0, %1, %2, %3" : "=v"(d) : "v"(a), "v"(b), "v"(c));
    return d;
}
__device__ __forceinline__ f32x2 pk_add(f32x2 a, f32x2 b) {
    f32x2 d;
    asm("v_pk_add_f32 %0, %1, %2" : "=v"(d) : "v"(a), "v"(b));
    return d;
}
__device__ __forceinline__ f32x2 pk_mul(f32x2 a, f32x2 b) {
    f32x2 d;
    asm("v_pk_mul_f32 %0, %1, %2" : "=v"(d) : "v"(a), "v"(b));
    return d;
}

// async global->LDS, 16B per lane. lds ptr must be wave-uniform (HW adds
// lane*16); the GLOBAL address is per-lane (enables source pre-swizzle).
__device__ __forceinline__ void gload16(const void* g, void* l) {
    __builtin_amdgcn_global_load_lds(
        (const __attribute__((address_space(1))) unsigned int*)g,
        (__attribute__((address_space(3))) unsigned int*)l,
        16, 0, 0);
}

// dst = { S0[31:16], S1[31:16] } packed bf16x2 word; sel via SGPR.
__device__ __forceinline__ unsigned int perm_hipack(unsigned int s0_hi,
                                                    unsigned int s1_lo,
                                                    unsigned int sel) {
    unsigned int d;
    asm("v_perm_b32 %0, %1, %2, %3" : "=v"(d) : "v"(s0_hi), "v"(s1_lo), "s"(sel));
    return d;
}

// 8 fp32 (two f32x4, k ascending) -> hi/lo bf16x8 fragments via v_perm.
// hi = top16(x); lo = top16(x - trunc16(x)). |x - hi - lo| <= 2^-14 |x|.
__device__ __forceinline__ void split8f(const f32x4 p0, const f32x4 p1,
                                        bf16x8& h, bf16x8& l,
                                        unsigned int sel) {
    typedef __attribute__((ext_vector_type(4))) unsigned int u32x4;
    union { u32x4 u; bf16x8 b; } H, L;
#define SPLIT_PAIR(ix, ax, ay)                                              \
    {                                                                       \
        float tx = __uint_as_float(__float_as_uint(ax) & 0xFFFF0000u);      \
        float ty = __uint_as_float(__float_as_uint(ay) & 0xFFFF0000u);      \
        float rx = (ax) - tx;                                               \
        float ry = (ay) - ty;                                               \
        H.u[ix] = perm_hipack(__float_as_uint(ay), __float_as_uint(ax), sel); \
        L.u[ix] = perm_hipack(__float_as_uint(ry), __float_as_uint(rx), sel); \
    }
    SPLIT_PAIR(0, p0.x, p0.y)
    SPLIT_PAIR(1, p0.z, p0.w)
    SPLIT_PAIR(2, p1.x, p1.y)
    SPLIT_PAIR(3, p1.z, p1.w)
#undef SPLIT_PAIR
    h = H.b;
    l = L.b;
}

// ---------------------------------------------------------------------------
// Kernel 1: Y = X @ W^T + bias via split-bf16 MFMA, fp32 DMA staging,
// HIGH-OCCUPANCY geometry: 32x64 tile, LDS [2 buf][96 row][32 k] f32 =
// 24 KiB -> 6 blocks/CU (grid 1536 = exactly 6/CU = 6 waves/SIMD).
// Rows 0-31 = A (X rows), rows 32-95 = B (W rows). 4 waves in 2x2; wave
// tile 16x32 = 1 A-frag x 2 B-frags of 16x16x32, 6 MFMA (3-term) per step.
// Staging: 3 gload16/thread/step, source granule XOR-swizzled
// ((lane&7)^(lane>>3)); LDS dest linear; frag reads apply the same XOR.
// ---------------------------------------------------------------------------
__global__ __launch_bounds__(256) void qkv_gemm_mfma(
    const float* __restrict__ Xq, const float* __restrict__ Xk, const float* __restrict__ Xv,
    const float* __restrict__ Wq, const float* __restrict__ Wk, const float* __restrict__ Wv,
    const float* __restrict__ bq, const float* __restrict__ bk, const float* __restrict__ bv,
    float* __restrict__ qkv_out)
{
    const int which = blockIdx.z;
    const float* __restrict__ X    = (which == 0) ? Xq : (which == 1) ? Xk : Xv;
    const float* __restrict__ W    = (which == 0) ? Wq : (which == 1) ? Wk : Wv;
    const float* __restrict__ bias = (which == 0) ? bq : (which == 1) ? bk : bv;
    float* __restrict__ Y = qkv_out + (size_t)which * B_SZ * D_SZ;

    const int t    = threadIdx.x;
    const int lane = t & 63;
    const int wv   = t >> 6;
    const int l15  = lane & 15;
    const int quad = lane >> 4;
    const int wm   = (wv >> 1) * 16;   // wave row offset (A region)
    const int wn   = (wv & 1) * 32;    // wave col offset (B region)
    const int m0   = blockIdx.x * 32;
    const int n0   = blockIdx.y * 64;

    const unsigned int sel = 0x07060302u;   // perm selector (SGPR)

    // [buf][row][k] f32: rows 0-31 = A tile, rows 32-95 = B tile; 24576 B
    __shared__ float lds[2][96][32];

    f32x4 acc[2] = {};

    // staging: thread covers 3 16B-granules (A, B-lo, B-hi); for all three
    // the LDS row is h*32 + wv*8 + lane/8 and row&7 = lane>>3, so the
    // source granule swizzle is the same: (lane&7) ^ ((lane>>3)&7).
    const int srow   = wv * 8 + (lane >> 3);                  // 0..31 in-region
    const int gcolsw = ((lane & 7) ^ ((lane >> 3) & 7)) * 4;  // swizzled col
    const float* gA  = X + (size_t)(m0 + srow) * D_SZ + gcolsw;
    const float* gB0 = W + (size_t)(n0 + srow) * D_SZ + gcolsw;
    const float* gB1 = W + (size_t)(n0 + 32 + srow) * D_SZ + gcolsw;

    auto stage = [&](int cur, int kk) {
        char* lb = (char*)&lds[cur][0][0] + (wv << 10);       // wave-uniform
        gload16(gA  + kk, lb);                                // rows  0..31
        gload16(gB0 + kk, lb + 4096);                         // rows 32..63
        gload16(gB1 + kk, lb + 8192);                         // rows 64..95
    };

    auto compute = [&](int cur) {
        const int sw = l15 & 7;
        const int g0 = (quad << 1) ^ sw;         // swizzled granule, k=quad*8
        const int g1 = ((quad << 1) | 1) ^ sw;   // swizzled granule, k=quad*8+4

        bf16x8 ah, al, bh[2], bl[2];
        {
            const float* rp = &lds[cur][wm + l15][0];
            f32x4 p0 = *(const f32x4*)(rp + (g0 << 2));
            f32x4 p1 = *(const f32x4*)(rp + (g1 << 2));
            split8f(p0, p1, ah, al, sel);
        }
#pragma unroll
        for (int ni = 0; ni < 2; ++ni) {
            const float* rp = &lds[cur][32 + wn + ni * 16 + l15][0];
            f32x4 p0 = *(const f32x4*)(rp + (g0 << 2));
            f32x4 p1 = *(const f32x4*)(rp + (g1 << 2));
            split8f(p0, p1, bh[ni], bl[ni], sel);
        }
#pragma unroll
        for (int ni = 0; ni < 2; ++ni) {
            acc[ni] = __builtin_amdgcn_mfma_f32_16x16x32_bf16(ah, bh[ni], acc[ni], 0, 0, 0);
            acc[ni] = __builtin_amdgcn_mfma_f32_16x16x32_bf16(al, bh[ni], acc[ni], 0, 0, 0);
            acc[ni] = __builtin_amdgcn_mfma_f32_16x16x32_bf16(ah, bl[ni], acc[ni], 0, 0, 0);
        }
    };

    stage(0, 0);
    __syncthreads();               // drains stage-0 DMA (auto vmcnt(0))
    int cur = 0;
    for (int it = 0; it < 15; ++it) {
        stage(cur ^ 1, (it + 1) * 32);   // async into other buffer
        compute(cur);                     // ds_reads + split + 6 MFMA cover
        __syncthreads();                  // drain next-buf DMA, publish
        cur ^= 1;
    }
    compute(cur);

    // epilogue: C/D layout col=lane&15, row=quad*4+reg (m89/m91-verified)
#pragma unroll
    for (int ni = 0; ni < 2; ++ni) {
        const int col = n0 + wn + ni * 16 + l15;
        const float bb = bias[col];
        const int row = m0 + wm + quad * 4;
#pragma unroll
        for (int rr = 0; rr < 4; ++rr) {
            Y[(size_t)(row + rr) * D_SZ + col] = acc[ni][rr] + bb;
        }
    }
}

// ---------------------------------------------------------------------------
// Kernel 2: per batch b, f(s) = sum_j exp2(s*kL_j)*v_j / sum_j exp2(s*kL_j);
// out[b,i] = f(q_i). kL = k*log2e applied at LDS staging. Phase 1: f on a
// 64-pt uniform grid over [qmin,qmax]; 4 threads per grid point (each
// sweeps 128 j's, 2 shfl_xor combine). Phase 2: Lagrange-cubic interp.
// (Byte-identical to rounds 10-15 -- control variable this round.)
// ---------------------------------------------------------------------------
__global__ __launch_bounds__(256) void attn_kernel(
    const float* __restrict__ qkv, float* __restrict__ out)
{
    const int b = blockIdx.x;
    const int t = threadIdx.x;

    const float* __restrict__ q = qkv + (size_t)b * D_SZ;
    const float* __restrict__ k = qkv + (size_t)B_SZ * D_SZ + (size_t)b * D_SZ;
    const float* __restrict__ v = qkv + (size_t)2 * B_SZ * D_SZ + (size_t)b * D_SZ;

    __shared__ __align__(16) float kk_s[4 * SEG];
    __shared__ __align__(16) float vv_s[4 * SEG];
    __shared__ __align__(16) float fgrid[NGRID];
    __shared__ float redmax[4], redmin[4];

    // ---- stage k*log2e, v to LDS (segmented), load this thread's q rows ----
    const int i0 = t, i1 = t + 256;
    const float q0 = q[i0];
    const float q1 = q[i1];
    {
        const int j   = 2 * t;
        const int pos = (j >> 7) * SEG + (j & 127);
        float2 kf = *(const float2*)&k[j];
        float2 vf = *(const float2*)&v[j];
        kf.x *= LOG2E;
        kf.y *= LOG2E;
        *(float2*)&kk_s[pos] = kf;
        *(float2*)&vv_s[pos] = vf;
    }

    // ---- q-range reduction (grid support) ----
    float qmax = fmaxf(q0, q1), qmin = fminf(q0, q1);
#pragma unroll
    for (int off = 32; off > 0; off >>= 1) {
        qmax = fmaxf(qmax, __shfl_xor(qmax, off));
        qmin = fminf(qmin, __shfl_xor(qmin, off));
    }
    const int wave = t >> 6;
    if ((t & 63) == 0) { redmax[wave] = qmax; redmin[wave] = qmin; }
    __syncthreads();   // also publishes kk_s/vv_s
    qmax = fmaxf(fmaxf(redmax[0], redmax[1]), fmaxf(redmax[2], redmax[3]));
    qmin = fminf(fminf(redmin[0], redmin[1]), fminf(redmin[2], redmin[3]));

    const float h    = fmaxf((qmax - qmin) * (1.0f / (float)(NGRID - 3)), 1e-30f);
    const float s0   = qmin - h;                 // grid: s_g = s0 + g*h
    const float invh = 1.0f / h;                 // q in [s_1, s_{NGRID-2}]

    // ---- phase 1: grid evaluation (4 threads per grid point) ----
    {
        const int   g   = t >> 2;
        const int   sub = t & 3;
        const int   jb  = sub * SEG;
        const float sg  = s0 + (float)g * h;
        const f32x2 sgg = {sg, sg};

        f32x2 dena = {0.f, 0.f}, denb = {0.f, 0.f};
        f32x2 numa = {0.f, 0.f}, numb = {0.f, 0.f};
#pragma unroll 4
        for (int jj = 0; jj < 128; jj += 4) {
            f32x4 kq = *(const f32x4*)&kk_s[jb + jj];
            f32x4 vq = *(const f32x4*)&vv_s[jb + jj];
            f32x2 ka = {kq.x, kq.y}, kb_ = {kq.z, kq.w};
            f32x2 va = {vq.x, vq.y}, vb_ = {vq.z, vq.w};

            f32x2 ea = pk_mul(sgg, ka);
            f32x2 eb = pk_mul(sgg, kb_);
            // in-place v_exp_f32 on the pair's own registers (no repack)
            ea.x = exp2_raw(ea.x); ea.y = exp2_raw(ea.y);
            eb.x = exp2_raw(eb.x); eb.y = exp2_raw(eb.y);

            dena = pk_add(dena, ea);
            denb = pk_add(denb, eb);
            numa = pk_fma(ea, va, numa);
            numb = pk_fma(eb, vb_, numb);
        }
        float den = (dena.x + dena.y) + (denb.x + denb.y);
        float num = (numa.x + numa.y) + (numb.x + numb.y);
        den += __shfl_xor(den, 1);  num += __shfl_xor(num, 1);
        den += __shfl_xor(den, 2);  num += __shfl_xor(num, 2);
        if (sub == 0) fgrid[g] = num / den;
    }
    __syncthreads();

    // ---- phase 2: cubic interpolation at q_i ----
#pragma unroll
    for (int r = 0; r < 2; ++r) {
        const float qi = (r == 0) ? q0 : q1;
        const int   ii = (r == 0) ? i0 : i1;

        float u  = (qi - s0) * invh;
        int   ic = (int)floorf(u);
        ic = (ic < 1) ? 1 : ((ic > NGRID - 3) ? (NGRID - 3) : ic);
        float uu = u - (float)ic;

        float f0 = fgrid[ic - 1];
        float f1 = fgrid[ic];
        float f2 = fgrid[ic + 1];
        float f3 = fgrid[ic + 2];

        const float um1 = uu - 1.0f, um2 = uu - 2.0f, up1 = uu + 1.0f;
        const float w0 = -uu * um1 * um2 * (1.0f / 6.0f);
        const float w1 =  up1 * um1 * um2 * 0.5f;
        const float w2 = -up1 * uu  * um2 * 0.5f;
        const float w3 =  up1 * uu  * um1 * (1.0f / 6.0f);

        out[(size_t)b * D_SZ + ii] = w0 * f0 + w1 * f1 + w2 * f2 + w3 * f3;
    }
}

extern "C" void kernel_launch(void* const* d_in, const int* in_sizes, int n_in,
                              void* d_out, int out_size, void* d_ws, size_t ws_size,
                              hipStream_t stream) {
    const float* query = (const float*)d_in[0];
    const float* key_  = (const float*)d_in[1];
    const float* value = (const float*)d_in[2];
    const float* Wq    = (const float*)d_in[3];
    const float* bq    = (const float*)d_in[4];
    const float* Wk    = (const float*)d_in[5];
    const float* bk    = (const float*)d_in[6];
    const float* Wv    = (const float*)d_in[7];
    const float* bv    = (const float*)d_in[8];
    float* out = (float*)d_out;

    // workspace: qkv fp32 [3][B][D] = 12.58 MB
    float* qkv = (float*)d_ws;

    dim3 g1(B_SZ / 32, D_SZ / 64, 3);
    qkv_gemm_mfma<<<g1, 256, 0, stream>>>(query, key_, value, Wq, Wk, Wv,
                                          bq, bk, bv, qkv);

    attn_kernel<<<B_SZ, 256, 0, stream>>>(qkv, out);
}

// Round 13
// 104.305 us; speedup vs baseline: 1.0591x; 1.0591x over previous
//
#include <hip/hip_runtime.h>

// Problem: B=2048, D=512, all fp32.
// q = query@Wq.T+bq ; k,v likewise. attn[b,i,j]=q_i*k_j (rank-1!),
// softmax over j, out[b,i] = sum_j softmax_j(q_i*k_j)*v_j.
//
// Round 17: REVERT to round-15 source (best measured: 105.2/105.6us).
// r16's 6-blocks/CU experiment regressed (+5us = doubled W-tile DMA);
// occupancy was the last untested gemm lever and is now nulled alongside
// barrier-drain removal (r7), LDS elimination (r12), scheduling pins
// (r13/r14), split-VALU removal (r0-r1), and BK doubling (r2).
// This restores the best-known state:
//  - gemm: 64x64 tile, 3 blocks/CU, BK=32, double-buffered LDS, DMA
//    staging (global_load_lds 16B) with XOR granule swizzle, in-register
//    v_perm hi/lo split, 12 MFMA 3-term split-bf16 per K-step.
//  - attn: per-batch tilted-mean f(s) on a 64-pt grid + cubic interp.
//
// Ledger (final): ~43.5us poison fill (harness, itself at HBM roofline) +
// ~25-30us harness resets/gaps + gemm ~21 + attn ~11 + 2 launch gaps.

#define B_SZ 2048
#define D_SZ 512
#define LOG2E 1.44269504088896340736f
#define NGRID 64
#define SEG 136   // 128 floats payload + 8 pad: segment s starts at bank 8s

typedef __attribute__((ext_vector_type(2))) float  f32x2;
typedef __attribute__((ext_vector_type(4))) float  f32x4;
typedef __attribute__((ext_vector_type(8))) short  bf16x8;   // MFMA A/B carrier

__device__ __forceinline__ float exp2_raw(float x) {
#if defined(__has_builtin) && __has_builtin(__builtin_amdgcn_exp2f)
    return __builtin_amdgcn_exp2f(x);
#else
    return exp2f(x);
#endif
}

// Forced packed fp32 math (compiler emits scalar for f32x2 exprs otherwise).
__device__ __forceinline__ f32x2 pk_fma(f32x2 a, f32x2 b, f32x2 c) {
    f32x2 d;
    asm("v_pk_fma_f32 %0, %1, %2, %3" : "=v"(d) : "v"(a), "v"(b), "v"(c));
    return d;
}
__device__ __forceinline__ f32x2 pk_add(f32x2 a, f32x2 b) {
    f32x2 d;
    asm("v_pk_add_f32 %0, %1, %2" : "=v"(d) : "v"(a), "v"(b));
    return d;
}
__device__ __forceinline__ f32x2 pk_mul(f32x2 a, f32x2 b) {
    f32x2 d;
    asm("v_pk_mul_f32 %0, %1, %2" : "=v"(d) : "v"(a), "v"(b));
    return d;
}

// async global->LDS, 16B per lane. lds ptr must be wave-uniform (HW adds
// lane*16); the GLOBAL address is per-lane (enables source pre-swizzle).
__device__ __forceinline__ void gload16(const void* g, void* l) {
    __builtin_amdgcn_global_load_lds(
        (const __attribute__((address_space(1))) unsigned int*)g,
        (__attribute__((address_space(3))) unsigned int*)l,
        16, 0, 0);
}

// dst = { S0[31:16], S1[31:16] } : packs two fp32 hi-halves (= bf16-trunc)
// into one VGPR, element order matching bf16x8 (first elem in low 16).
// sel = 0x07060302; VOP3 forbids literals -> sel comes in via SGPR.
__device__ __forceinline__ unsigned int perm_hipack(unsigned int s0_hi,
                                                    unsigned int s1_lo,
                                                    unsigned int sel) {
    unsigned int d;
    asm("v_perm_b32 %0, %1, %2, %3" : "=v"(d) : "v"(s0_hi), "v"(s1_lo), "s"(sel));
    return d;
}

// 8 fp32 (two f32x4, k ascending) -> hi/lo bf16x8 fragments via v_perm.
// hi = top16(x); lo = top16(x - trunc16(x)). |x - hi - lo| <= 2^-14 |x|.
__device__ __forceinline__ void split8f(const f32x4 p0, const f32x4 p1,
                                        bf16x8& h, bf16x8& l,
                                        unsigned int sel) {
    typedef __attribute__((ext_vector_type(4))) unsigned int u32x4;
    union { u32x4 u; bf16x8 b; } H, L;
#define SPLIT_PAIR(ix, ax, ay)                                              \
    {                                                                       \
        float tx = __uint_as_float(__float_as_uint(ax) & 0xFFFF0000u);      \
        float ty = __uint_as_float(__float_as_uint(ay) & 0xFFFF0000u);      \
        float rx = (ax) - tx;                                               \
        float ry = (ay) - ty;                                               \
        H.u[ix] = perm_hipack(__float_as_uint(ay), __float_as_uint(ax), sel); \
        L.u[ix] = perm_hipack(__float_as_uint(ry), __float_as_uint(rx), sel); \
    }
    SPLIT_PAIR(0, p0.x, p0.y)
    SPLIT_PAIR(1, p0.z, p0.w)
    SPLIT_PAIR(2, p1.x, p1.y)
    SPLIT_PAIR(3, p1.z, p1.w)
#undef SPLIT_PAIR
    h = H.b;
    l = L.b;
}

// ---------------------------------------------------------------------------
// Kernel 1: Y = X @ W^T + bias via split-bf16 MFMA, staging fp32 directly.
// 64x64 tile, 256 thr = 4 waves (2x2, 32x32 each -> 2x2 frags of 16x16x32).
// BK=32, LDS [2 buf][2 op][64 row][32 k] fp32 = 32 KiB (3 blocks/CU).
// Staging: wave w stages op w>>1, row-half w&1: 4x gload16/lane, source
// granule XOR-swizzled (g^(row&7)); LDS dest linear. Frag reads apply the
// same XOR -> uniform bank use. Split to hi/lo bf16 in regs, 12 MFMA/step.
// ---------------------------------------------------------------------------
__global__ __launch_bounds__(256) void qkv_gemm_mfma(
    const float* __restrict__ Xq, const float* __restrict__ Xk, const float* __restrict__ Xv,
    const float* __restrict__ Wq, const float* __restrict__ Wk, const float* __restrict__ Wv,
    const float* __restrict__ bq, const float* __restrict__ bk, const float* __restrict__ bv,
    float* __restrict__ qkv_out)
{
    const int which = blockIdx.z;
    const float* __restrict__ X    = (which == 0) ? Xq : (which == 1) ? Xk : Xv;
    const float* __restrict__ W    = (which == 0) ? Wq : (which == 1) ? Wk : Wv;
    const float* __restrict__ bias = (which == 0) ? bq : (which == 1) ? bk : bv;
    float* __restrict__ Y = qkv_out + (size_t)which * B_SZ * D_SZ;

    const int t    = threadIdx.x;
    const int lane = t & 63;
    const int wv   = t >> 6;
    const int l15  = lane & 15;
    const int quad = lane >> 4;
    const int wm   = (wv >> 1) * 32;
    const int wn   = (wv & 1) * 32;
    const int m0   = blockIdx.x * 64;
    const int n0   = blockIdx.y * 64;

    const unsigned int sel = 0x07060302u;   // perm selector (SGPR)

    // [buf][op][row][k] fp32 ; op: 0=A(X rows) 1=B(W rows) ; 32768 B
    __shared__ float lds[2][2][64][32];

    f32x4 acc[2][2] = {};

    // wave-specialized staging: op = wv>>1, row half = wv&1
    const int   op    = wv >> 1;
    const int   wsub  = wv & 1;
    const float* __restrict__ gsrc = (op == 0) ? X : W;
    const int   tile0 = (op == 0) ? m0 : n0;
    // lane covers (row = wsub*32 + h*8 + lane/8, granule g = lane&7);
    // source granule pre-swizzled: g ^ (row&7) = (lane&7) ^ ((lane>>3)&7)
    const int grow   = tile0 + wsub * 32 + (lane >> 3);
    const int gcolsw = ((lane & 7) ^ ((lane >> 3) & 7)) * 4;
    const float* gl0 = gsrc + (size_t)grow * D_SZ + gcolsw;

    auto stage = [&](int cur, int kk) {
        char* lb = (char*)&lds[cur][op][wsub * 32][0];    // wave-uniform
        const float* g = gl0 + kk;
#pragma unroll
        for (int h = 0; h < 4; ++h) {
            gload16(g + (size_t)(h * 8) * D_SZ, lb + h * 1024);
        }
    };

    auto compute = [&](int cur) {
        bf16x8 a_h[2], a_l[2], b_h[2], b_l[2];
        const int sw = l15 & 7;                 // row&7 for frag rows
        const int g0 = (quad << 1) ^ sw;        // swizzled granule of k=quad*8
        const int g1 = ((quad << 1) | 1) ^ sw;  // swizzled granule of k=quad*8+4
#pragma unroll
        for (int mi = 0; mi < 2; ++mi) {
            const float* rp = &lds[cur][0][wm + mi * 16 + l15][0];
            f32x4 p0 = *(const f32x4*)(rp + (g0 << 2));
            f32x4 p1 = *(const f32x4*)(rp + (g1 << 2));
            split8f(p0, p1, a_h[mi], a_l[mi], sel);
        }
#pragma unroll
        for (int ni = 0; ni < 2; ++ni) {
            const float* rp = &lds[cur][1][wn + ni * 16 + l15][0];
            f32x4 p0 = *(const f32x4*)(rp + (g0 << 2));
            f32x4 p1 = *(const f32x4*)(rp + (g1 << 2));
            split8f(p0, p1, b_h[ni], b_l[ni], sel);
        }
#pragma unroll
        for (int mi = 0; mi < 2; ++mi)
#pragma unroll
            for (int ni = 0; ni < 2; ++ni) {
                acc[mi][ni] = __builtin_amdgcn_mfma_f32_16x16x32_bf16(a_h[mi], b_h[ni], acc[mi][ni], 0, 0, 0);
                acc[mi][ni] = __builtin_amdgcn_mfma_f32_16x16x32_bf16(a_l[mi], b_h[ni], acc[mi][ni], 0, 0, 0);
                acc[mi][ni] = __builtin_amdgcn_mfma_f32_16x16x32_bf16(a_h[mi], b_l[ni], acc[mi][ni], 0, 0, 0);
            }
    };

    stage(0, 0);
    __syncthreads();               // drains stage-0 DMA (auto vmcnt(0))
    int cur = 0;
    for (int it = 0; it < 15; ++it) {
        stage(cur ^ 1, (it + 1) * 32);   // async into other buffer
        compute(cur);                     // ds_reads + split + 12 MFMA cover
        __syncthreads();                  // drain next-buf DMA, publish
        cur ^= 1;
    }
    compute(cur);

    // epilogue: C/D layout col=lane&15, row=quad*4+reg (m89/m91-verified)
#pragma unroll
    for (int ni = 0; ni < 2; ++ni) {
        const int col = n0 + wn + ni * 16 + l15;
        const float bb = bias[col];
#pragma unroll
        for (int mi = 0; mi < 2; ++mi) {
            const int row = m0 + wm + mi * 16 + quad * 4;
#pragma unroll
            for (int rr = 0; rr < 4; ++rr) {
                Y[(size_t)(row + rr) * D_SZ + col] = acc[mi][ni][rr] + bb;
            }
        }
    }
}

// ---------------------------------------------------------------------------
// Kernel 2: per batch b, f(s) = sum_j exp2(s*kL_j)*v_j / sum_j exp2(s*kL_j);
// out[b,i] = f(q_i). kL = k*log2e applied at LDS staging. Phase 1: f on a
// 64-pt uniform grid over [qmin,qmax]; 4 threads per grid point (each
// sweeps 128 j's, 2 shfl_xor combine). Phase 2: Lagrange-cubic interp.
// ---------------------------------------------------------------------------
__global__ __launch_bounds__(256) void attn_kernel(
    const float* __restrict__ qkv, float* __restrict__ out)
{
    const int b = blockIdx.x;
    const int t = threadIdx.x;

    const float* __restrict__ q = qkv + (size_t)b * D_SZ;
    const float* __restrict__ k = qkv + (size_t)B_SZ * D_SZ + (size_t)b * D_SZ;
    const float* __restrict__ v = qkv + (size_t)2 * B_SZ * D_SZ + (size_t)b * D_SZ;

    __shared__ __align__(16) float kk_s[4 * SEG];
    __shared__ __align__(16) float vv_s[4 * SEG];
    __shared__ __align__(16) float fgrid[NGRID];
    __shared__ float redmax[4], redmin[4];

    // ---- stage k*log2e, v to LDS (segmented), load this thread's q rows ----
    const int i0 = t, i1 = t + 256;
    const float q0 = q[i0];
    const float q1 = q[i1];
    {
        const int j   = 2 * t;
        const int pos = (j >> 7) * SEG + (j & 127);
        float2 kf = *(const float2*)&k[j];
        float2 vf = *(const float2*)&v[j];
        kf.x *= LOG2E;
        kf.y *= LOG2E;
        *(float2*)&kk_s[pos] = kf;
        *(float2*)&vv_s[pos] = vf;
    }

    // ---- q-range reduction (grid support) ----
    float qmax = fmaxf(q0, q1), qmin = fminf(q0, q1);
#pragma unroll
    for (int off = 32; off > 0; off >>= 1) {
        qmax = fmaxf(qmax, __shfl_xor(qmax, off));
        qmin = fminf(qmin, __shfl_xor(qmin, off));
    }
    const int wave = t >> 6;
    if ((t & 63) == 0) { redmax[wave] = qmax; redmin[wave] = qmin; }
    __syncthreads();   // also publishes kk_s/vv_s
    qmax = fmaxf(fmaxf(redmax[0], redmax[1]), fmaxf(redmax[2], redmax[3]));
    qmin = fminf(fminf(redmin[0], redmin[1]), fminf(redmin[2], redmin[3]));

    const float h    = fmaxf((qmax - qmin) * (1.0f / (float)(NGRID - 3)), 1e-30f);
    const float s0   = qmin - h;                 // grid: s_g = s0 + g*h
    const float invh = 1.0f / h;                 // q in [s_1, s_{NGRID-2}]

    // ---- phase 1: grid evaluation (4 threads per grid point) ----
    {
        const int   g   = t >> 2;
        const int   sub = t & 3;
        const int   jb  = sub * SEG;
        const float sg  = s0 + (float)g * h;
        const f32x2 sgg = {sg, sg};

        f32x2 dena = {0.f, 0.f}, denb = {0.f, 0.f};
        f32x2 numa = {0.f, 0.f}, numb = {0.f, 0.f};
#pragma unroll 4
        for (int jj = 0; jj < 128; jj += 4) {
            f32x4 kq = *(const f32x4*)&kk_s[jb + jj];
            f32x4 vq = *(const f32x4*)&vv_s[jb + jj];
            f32x2 ka = {kq.x, kq.y}, kb_ = {kq.z, kq.w};
            f32x2 va = {vq.x, vq.y}, vb_ = {vq.z, vq.w};

            f32x2 ea = pk_mul(sgg, ka);
            f32x2 eb = pk_mul(sgg, kb_);
            // in-place v_exp_f32 on the pair's own registers (no repack)
            ea.x = exp2_raw(ea.x); ea.y = exp2_raw(ea.y);
            eb.x = exp2_raw(eb.x); eb.y = exp2_raw(eb.y);

            dena = pk_add(dena, ea);
            denb = pk_add(denb, eb);
            numa = pk_fma(ea, va, numa);
            numb = pk_fma(eb, vb_, numb);
        }
        float den = (dena.x + dena.y) + (denb.x + denb.y);
        float num = (numa.x + numa.y) + (numb.x + numb.y);
        den += __shfl_xor(den, 1);  num += __shfl_xor(num, 1);
        den += __shfl_xor(den, 2);  num += __shfl_xor(num, 2);
        if (sub == 0) fgrid[g] = num / den;
    }
    __syncthreads();

    // ---- phase 2: cubic interpolation at q_i ----
#pragma unroll
    for (int r = 0; r < 2; ++r) {
        const float qi = (r == 0) ? q0 : q1;
        const int   ii = (r == 0) ? i0 : i1;

        float u  = (qi - s0) * invh;
        int   ic = (int)floorf(u);
        ic = (ic < 1) ? 1 : ((ic > NGRID - 3) ? (NGRID - 3) : ic);
        float uu = u - (float)ic;

        float f0 = fgrid[ic - 1];
        float f1 = fgrid[ic];
        float f2 = fgrid[ic + 1];
        float f3 = fgrid[ic + 2];

        const float um1 = uu - 1.0f, um2 = uu - 2.0f, up1 = uu + 1.0f;
        const float w0 = -uu * um1 * um2 * (1.0f / 6.0f);
        const float w1 =  up1 * um1 * um2 * 0.5f;
        const float w2 = -up1 * uu  * um2 * 0.5f;
        const float w3 =  up1 * uu  * um1 * (1.0f / 6.0f);

        out[(size_t)b * D_SZ + ii] = w0 * f0 + w1 * f1 + w2 * f2 + w3 * f3;
    }
}

extern "C" void kernel_launch(void* const* d_in, const int* in_sizes, int n_in,
                              void* d_out, int out_size, void* d_ws, size_t ws_size,
                              hipStream_t stream) {
    const float* query = (const float*)d_in[0];
    const float* key_  = (const float*)d_in[1];
    const float* value = (const float*)d_in[2];
    const float* Wq    = (const float*)d_in[3];
    const float* bq    = (const float*)d_in[4];
    const float* Wk    = (const float*)d_in[5];
    const float* bk    = (const float*)d_in[6];
    const float* Wv    = (const float*)d_in[7];
    const float* bv    = (const float*)d_in[8];
    float* out = (float*)d_out;

    // workspace: qkv fp32 [3][B][D] = 12.58 MB
    float* qkv = (float*)d_ws;

    dim3 g1(B_SZ / 64, D_SZ / 64, 3);
    qkv_gemm_mfma<<<g1, 256, 0, stream>>>(query, key_, value, Wq, Wk, Wv,
                                          bq, bk, bv, qkv);

    attn_kernel<<<B_SZ, 256, 0, stream>>>(qkv, out);
}